// Round 1
// baseline (799.983 us; speedup 1.0000x reference)
//
#include <hip/hip_runtime.h>
#include <hip/hip_bf16.h>
#include <stdint.h>

#define IN_F 4096
#define OUT_F 4096
#define NE 64
#define TOPK 16
#define RD 16
#define BOT 512
#define NTOK 16384

typedef __attribute__((ext_vector_type(8))) short short8;
typedef __attribute__((ext_vector_type(4))) float floatx4;
typedef __attribute__((ext_vector_type(2))) double double2v;

__device__ __forceinline__ unsigned short f2bf_ru(float f) {
  unsigned int u = __float_as_uint(f);
  return (unsigned short)((u + 0x8000u) >> 16);
}
__device__ __forceinline__ unsigned short f2bf_rne(float f) {
  unsigned int u = __float_as_uint(f);
  return (unsigned short)((u + 0x7FFFu + ((u >> 16) & 1u)) >> 16);
}

// ---------------- prep: convert A_w, B_w to bf16 ----------------
__global__ __launch_bounds__(256) void prep_kernel(
    const float* __restrict__ A_w, const float* __restrict__ B_w,
    unsigned short* __restrict__ Abf, unsigned short* __restrict__ Bbf) {
  int i = blockIdx.x * 256 + threadIdx.x;
  if (i < BOT * IN_F) {
    Abf[i] = f2bf_rne(A_w[i]);
    Bbf[i] = f2bf_rne(B_w[i]);  // B_w is OUT_F*BOT == BOT*IN_F elements too
  }
}

// ---------------- router: fp64 q, scores, top-16, softmax -> dense gate ----------------
// block = 256 threads, 32 tokens per block, grid = 512
__global__ __launch_bounds__(256) void router_kernel(
    const float* __restrict__ x, const float* __restrict__ Wq,
    const float* __restrict__ keys, float* __restrict__ gate) {
  __shared__ double x_lds[32][132];   // padded to break bank conflicts
  __shared__ double wq_lds[16][132];
  __shared__ double q_lds[32][16];
  __shared__ double sc[32][64];
  const int tid = threadIdx.x;
  const size_t t0 = (size_t)blockIdx.x * 32;
  const int r = tid & 15, tg = tid >> 4;
  double acc0 = 0.0, acc1 = 0.0;

  for (int kc = 0; kc < IN_F; kc += 128) {
    __syncthreads();
    // stage x chunk (32 rows x 128 floats) as fp64
    for (int i = 0; i < 4; i++) {
      int f = i * 256 + tid;
      int row = f >> 5, c = (f & 31) * 4;
      float4 v = *(const float4*)(x + (t0 + row) * IN_F + kc + c);
      x_lds[row][c] = (double)v.x; x_lds[row][c + 1] = (double)v.y;
      x_lds[row][c + 2] = (double)v.z; x_lds[row][c + 3] = (double)v.w;
    }
    // stage Wq chunk (16 rows x 128 floats) as fp64
    for (int i = 0; i < 2; i++) {
      int f = i * 256 + tid;
      int row = f >> 5, c = (f & 31) * 4;
      float4 v = *(const float4*)(Wq + (size_t)row * IN_F + kc + c);
      wq_lds[row][c] = (double)v.x; wq_lds[row][c + 1] = (double)v.y;
      wq_lds[row][c + 2] = (double)v.z; wq_lds[row][c + 3] = (double)v.w;
    }
    __syncthreads();
    const double* xr0 = x_lds[tg * 2];
    const double* xr1 = x_lds[tg * 2 + 1];
    const double* wr = wq_lds[r];
#pragma unroll 8
    for (int k = 0; k < 128; k += 2) {
      double2v w = *(const double2v*)(wr + k);
      double2v a = *(const double2v*)(xr0 + k);
      double2v b = *(const double2v*)(xr1 + k);
      acc0 += a.x * w.x; acc0 += a.y * w.y;
      acc1 += b.x * w.x; acc1 += b.y * w.y;
    }
  }
  q_lds[tg * 2][r] = acc0;
  q_lds[tg * 2 + 1][r] = acc1;
  __syncthreads();

  // scores[t][e] = sum_r q[t][r] * keys[e][r]   (fp64)
  {
    int t = tid >> 3, e0 = (tid & 7) * 8;
    for (int e = e0; e < e0 + 8; e++) {
      double s = 0.0;
      for (int rr = 0; rr < 16; rr++) s += q_lds[t][rr] * (double)keys[e * RD + rr];
      sc[t][e] = s;
    }
  }
  __syncthreads();

  // top-16 (ties -> lowest index, matching lax.top_k), softmax, scatter
  if (tid < 32) {
    int t = tid;
    double vals[16]; int idx[16];
    unsigned long long used = 0ull;
    for (int s = 0; s < 16; s++) {
      double best = -1e300; int bi = 0;
      for (int e = 0; e < 64; e++) {
        double v = sc[t][e];
        if (!((used >> e) & 1ull) && v > best) { best = v; bi = e; }
      }
      used |= (1ull << bi);
      vals[s] = best; idx[s] = bi;
    }
    double mx = vals[0], sum = 0.0, w[16];
    for (int i = 0; i < 16; i++) { w[i] = exp(vals[i] - mx); sum += w[i]; }
    double inv = 1.0 / sum;
    float* grow = gate + (t0 + t) * NE;
    for (int e = 0; e < 64; e++) grow[e] = 0.0f;
    for (int i = 0; i < 16; i++) grow[idx[i]] = (float)(w[i] * inv);
  }
}

// ---------------- stage A: z_gated[16384,512] = (x @ A^T) * gate, bf16 out ----------------
// 128x128 tile, BK=32, 256 threads (2x2 waves of 64x64), grid = 512
__global__ __launch_bounds__(256) void stageA_kernel(
    const float* __restrict__ x, const unsigned short* __restrict__ Abf,
    const float* __restrict__ gate, unsigned short* __restrict__ z) {
  __shared__ unsigned short As[128 * 32];
  __shared__ unsigned short Bs[128 * 32];
  __shared__ float gl[128 * 16];
  const int tid = threadIdx.x;
  const int bid = blockIdx.x;
  const int mt = (bid & 7) + (bid >> 5) * 8;  // XCD swizzle: same m-tile -> same XCD
  const int nt = (bid >> 3) & 3;
  const size_t m0 = (size_t)mt * 128;
  const int n0 = nt * 128;

  // gate tile: 128 tokens x 16 experts covered by this n-range
  for (int i = 0; i < 8; i++) {
    int f = i * 256 + tid;
    gl[f] = gate[(m0 + (f >> 4)) * NE + (n0 >> 3) + (f & 15)];
  }
  const int wid = tid >> 6, lane = tid & 63;
  const int wm = (wid & 1) * 64, wn = (wid >> 1) * 64;
  const int lr = lane & 15, lq = lane >> 4;
  floatx4 acc[4][4];
  for (int i = 0; i < 4; i++)
    for (int j = 0; j < 4; j++) acc[i][j] = 0.0f;

  for (int k0 = 0; k0 < IN_F; k0 += 32) {
    __syncthreads();
    // x (fp32) -> As (bf16): 128 rows x 32
    {
      int c4 = (tid & 7) * 4;
      int rbase = tid >> 3;
      for (int p = 0; p < 4; p++) {
        int row = p * 32 + rbase;
        float4 v = *(const float4*)(x + (m0 + row) * IN_F + k0 + c4);
        ushort4 h;
        h.x = f2bf_ru(v.x); h.y = f2bf_ru(v.y);
        h.z = f2bf_ru(v.z); h.w = f2bf_ru(v.w);
        *(ushort4*)(As + row * 32 + c4) = h;
      }
    }
    // Abf (bf16) -> Bs: 128 rows x 32
    for (int p = 0; p < 2; p++) {
      int f = p * 256 + tid;
      int row = f >> 2, c8 = (f & 3) * 8;
      float4 v = *(const float4*)(Abf + (size_t)(n0 + row) * IN_F + k0 + c8);
      *(float4*)(Bs + row * 32 + c8) = v;
    }
    __syncthreads();
    short8 a[4], b[4];
    for (int i = 0; i < 4; i++) a[i] = *(const short8*)(As + (wm + i * 16 + lr) * 32 + lq * 8);
    for (int j = 0; j < 4; j++) b[j] = *(const short8*)(Bs + (wn + j * 16 + lr) * 32 + lq * 8);
    for (int i = 0; i < 4; i++)
      for (int j = 0; j < 4; j++)
        acc[i][j] = __builtin_amdgcn_mfma_f32_16x16x32_bf16(a[i], b[j], acc[i][j], 0, 0, 0);
  }
  // epilogue: gate + bf16 store
  for (int i = 0; i < 4; i++) {
    for (int j = 0; j < 4; j++) {
      int cl = wn + j * 16 + lr;
      int el = cl >> 3;
      for (int g = 0; g < 4; g++) {
        int rl = wm + i * 16 + lq * 4 + g;
        float v = acc[i][j][g] * gl[rl * 16 + el];
        z[(m0 + rl) * BOT + n0 + cl] = f2bf_ru(v);
      }
    }
  }
}

// ---------------- stage B: out[16384,4096] = z_gated @ B^T * 2.0 ----------------
// 128x128 tile, BK=32, grid = 4096
__global__ __launch_bounds__(256) void stageB_kernel(
    const unsigned short* __restrict__ z, const unsigned short* __restrict__ Bbf,
    float* __restrict__ out) {
  __shared__ unsigned short As[128 * 32];
  __shared__ unsigned short Bs[128 * 32];
  const int tid = threadIdx.x;
  const int bid = blockIdx.x;
  const int mt = (bid & 7) + (bid >> 8) * 8;  // XCD swizzle
  const int nt = (bid >> 3) & 31;
  const size_t m0 = (size_t)mt * 128;
  const int n0 = nt * 128;
  const int wid = tid >> 6, lane = tid & 63;
  const int wm = (wid & 1) * 64, wn = (wid >> 1) * 64;
  const int lr = lane & 15, lq = lane >> 4;
  floatx4 acc[4][4];
  for (int i = 0; i < 4; i++)
    for (int j = 0; j < 4; j++) acc[i][j] = 0.0f;

  for (int k0 = 0; k0 < BOT; k0 += 32) {
    __syncthreads();
    for (int p = 0; p < 2; p++) {
      int f = p * 256 + tid;
      int row = f >> 2, c8 = (f & 3) * 8;
      *(float4*)(As + row * 32 + c8) =
          *(const float4*)(z + (m0 + row) * BOT + k0 + c8);
      *(float4*)(Bs + row * 32 + c8) =
          *(const float4*)(Bbf + (size_t)(n0 + row) * BOT + k0 + c8);
    }
    __syncthreads();
    short8 a[4], b[4];
    for (int i = 0; i < 4; i++) a[i] = *(const short8*)(As + (wm + i * 16 + lr) * 32 + lq * 8);
    for (int j = 0; j < 4; j++) b[j] = *(const short8*)(Bs + (wn + j * 16 + lr) * 32 + lq * 8);
    for (int i = 0; i < 4; i++)
      for (int j = 0; j < 4; j++)
        acc[i][j] = __builtin_amdgcn_mfma_f32_16x16x32_bf16(a[i], b[j], acc[i][j], 0, 0, 0);
  }
  for (int i = 0; i < 4; i++) {
    for (int j = 0; j < 4; j++) {
      int cl = wn + j * 16 + lr;
      for (int g = 0; g < 4; g++) {
        int rl = wm + i * 16 + lq * 4 + g;
        out[(m0 + rl) * OUT_F + n0 + cl] = acc[i][j][g] * 2.0f;  // SCALING = 32/16
      }
    }
  }
}

extern "C" void kernel_launch(void* const* d_in, const int* in_sizes, int n_in,
                              void* d_out, int out_size, void* d_ws, size_t ws_size,
                              hipStream_t stream) {
  const float* x    = (const float*)d_in[0];
  const float* A_w  = (const float*)d_in[1];
  const float* B_w  = (const float*)d_in[2];
  const float* Wq   = (const float*)d_in[3];
  const float* keys = (const float*)d_in[4];
  float* out = (float*)d_out;

  char* ws = (char*)d_ws;
  float* gate          = (float*)ws;                              // 16384*64*4   = 4  MB
  unsigned short* z    = (unsigned short*)(ws + (4 << 20));       // 16384*512*2  = 16 MB
  unsigned short* Abf  = (unsigned short*)(ws + (4 << 20) + 16777216);  // 4 MB
  unsigned short* Bbf  = Abf + BOT * IN_F;                        // 4 MB

  hipLaunchKernelGGL(prep_kernel, dim3(8192), dim3(256), 0, stream, A_w, B_w, Abf, Bbf);
  hipLaunchKernelGGL(router_kernel, dim3(512), dim3(256), 0, stream, x, Wq, keys, gate);
  hipLaunchKernelGGL(stageA_kernel, dim3(512), dim3(256), 0, stream, x, Abf, gate, z);
  hipLaunchKernelGGL(stageB_kernel, dim3(4096), dim3(256), 0, stream, z, Bbf, out);
}